// Round 1
// baseline (1830.922 us; speedup 1.0000x reference)
//
#include <hip/hip_runtime.h>
#include <math.h>

#define DIM_   1024
#define NHEADS 16
#define HDIM   64
#define SEQ    2048
#define BATCH  2

// ---------------------------------------------------------------------------
// GEMM: C[M][N] = A[M][K] * B[N][K]^T  (+ optional bias[N])
// 64x64 output tile, BK=16, 256 threads, 4x4 micro-tile per thread.
// LDS stored transposed [k][m] with stride 68 (pad) to avoid bank conflicts.
// ---------------------------------------------------------------------------
template <bool BIAS>
__global__ __launch_bounds__(256) void gemm_abt(const float* __restrict__ A,
                                                const float* __restrict__ B,
                                                const float* __restrict__ bias,
                                                float* __restrict__ C,
                                                int M, int N, int K) {
    __shared__ float As[16 * 68];
    __shared__ float Bs[16 * 68];
    const int tid  = threadIdx.x;
    const int m0   = blockIdx.y * 64;
    const int n0   = blockIdx.x * 64;
    const int lrow = tid >> 2;          // 0..63
    const int lcol = (tid & 3) << 2;    // 0,4,8,12
    const int tm   = tid >> 4;          // 0..15
    const int tn   = tid & 15;          // 0..15

    float acc[4][4] = {};

    for (int k0 = 0; k0 < K; k0 += 16) {
        float4 a = *(const float4*)(A + (size_t)(m0 + lrow) * K + k0 + lcol);
        float4 b = *(const float4*)(B + (size_t)(n0 + lrow) * K + k0 + lcol);
        __syncthreads();
        As[(lcol + 0) * 68 + lrow] = a.x;
        As[(lcol + 1) * 68 + lrow] = a.y;
        As[(lcol + 2) * 68 + lrow] = a.z;
        As[(lcol + 3) * 68 + lrow] = a.w;
        Bs[(lcol + 0) * 68 + lrow] = b.x;
        Bs[(lcol + 1) * 68 + lrow] = b.y;
        Bs[(lcol + 2) * 68 + lrow] = b.z;
        Bs[(lcol + 3) * 68 + lrow] = b.w;
        __syncthreads();
#pragma unroll
        for (int kk = 0; kk < 16; ++kk) {
            float ar[4], br[4];
#pragma unroll
            for (int i = 0; i < 4; ++i) ar[i] = As[kk * 68 + tm * 4 + i];
#pragma unroll
            for (int j = 0; j < 4; ++j) br[j] = Bs[kk * 68 + tn * 4 + j];
#pragma unroll
            for (int i = 0; i < 4; ++i)
#pragma unroll
                for (int j = 0; j < 4; ++j)
                    acc[i][j] = fmaf(ar[i], br[j], acc[i][j]);
        }
    }

#pragma unroll
    for (int i = 0; i < 4; ++i) {
        float4 o;
        o.x = acc[i][0]; o.y = acc[i][1]; o.z = acc[i][2]; o.w = acc[i][3];
        if (BIAS) {
            o.x += bias[n0 + tn * 4 + 0];
            o.y += bias[n0 + tn * 4 + 1];
            o.z += bias[n0 + tn * 4 + 2];
            o.w += bias[n0 + tn * 4 + 3];
        }
        *(float4*)(C + (size_t)(m0 + tm * 4 + i) * N + n0 + tn * 4) = o;
    }
}

// ---------------------------------------------------------------------------
// RoPE applied in place to q and k thirds of the qkv buffer.
// One thread handles one (token, {q|k}, head) = 64 contiguous floats.
// out[j] = x[2j]*cos - x[2j+1]*sin ; out[32+j] = x[2j]*sin + x[2j+1]*cos
// freq_j = 10000^(-j/32), angle = s * freq_j
// ---------------------------------------------------------------------------
__global__ __launch_bounds__(256) void rope_kernel(float* __restrict__ qkv) {
    const int gid   = blockIdx.x * 256 + threadIdx.x;  // 0 .. B*S*2*NH-1
    const int m     = gid >> 5;        // b*SEQ + s
    const int rr    = gid & 31;
    const int which = rr >> 4;         // 0=q, 1=k
    const int h     = rr & 15;
    const int s     = m & (SEQ - 1);

    float* p = qkv + (size_t)m * (3 * DIM_) + which * DIM_ + h * HDIM;

    float x[64];
#pragma unroll
    for (int i = 0; i < 16; ++i) {
        float4 v = *(const float4*)(p + i * 4);
        x[i * 4 + 0] = v.x; x[i * 4 + 1] = v.y;
        x[i * 4 + 2] = v.z; x[i * 4 + 3] = v.w;
    }

    float o[64];
    const float kf = 0.28782313662425572f;  // ln(10000)/32
#pragma unroll
    for (int j = 0; j < 32; ++j) {
        const float freq = expf(-kf * (float)j);
        const float ang  = (float)s * freq;
        float sn, cs;
        sincosf(ang, &sn, &cs);
        o[j]      = x[2 * j] * cs - x[2 * j + 1] * sn;
        o[32 + j] = x[2 * j] * sn + x[2 * j + 1] * cs;
    }

#pragma unroll
    for (int i = 0; i < 16; ++i) {
        float4 v;
        v.x = o[i * 4 + 0]; v.y = o[i * 4 + 1];
        v.z = o[i * 4 + 2]; v.w = o[i * 4 + 3];
        *(float4*)(p + i * 4) = v;
    }
}

// ---------------------------------------------------------------------------
// Flash-style attention (fp32). Grid: (SEQ/16, BATCH*NHEADS), 256 threads.
// Each block: 16 queries x full KV stream in 64-row tiles. Online softmax.
// Thread t owns row r=t>>4 and 4 columns c4=(t&15)*4 (both for scores and O).
// ---------------------------------------------------------------------------
__global__ __launch_bounds__(256) void attn_kernel(const float* __restrict__ qkv,
                                                   float* __restrict__ out) {
    const int bh  = blockIdx.y;
    const int b   = bh >> 4;
    const int h   = bh & 15;
    const int q0  = blockIdx.x * 16;
    const int tid = threadIdx.x;
    const int r   = tid >> 4;          // 0..15 query row
    const int c4  = (tid & 15) << 2;   // 0..60

    __shared__ float Qs[16 * 65];
    __shared__ float Ks[64 * 65];
    __shared__ float Vs[64 * 64];
    __shared__ float Ps[16 * 64];

    const size_t rs   = 3 * DIM_;
    const float* base = qkv + (size_t)b * SEQ * rs + h * HDIM;

    {   // load Q tile 16x64
        const int qr = tid >> 4;
        const int qc = (tid & 15) << 2;
        float4 v = *(const float4*)(base + (size_t)(q0 + qr) * rs + qc);
        Qs[qr * 65 + qc + 0] = v.x;
        Qs[qr * 65 + qc + 1] = v.y;
        Qs[qr * 65 + qc + 2] = v.z;
        Qs[qr * 65 + qc + 3] = v.w;
    }
    __syncthreads();

    float qreg[64];
#pragma unroll
    for (int d = 0; d < 64; ++d) qreg[d] = Qs[r * 65 + d];

    float4 o = {0.f, 0.f, 0.f, 0.f};
    float m = -INFINITY, l = 0.f;

    for (int k0 = 0; k0 < SEQ; k0 += 64) {
        __syncthreads();   // previous iteration done with Ks/Vs/Ps
#pragma unroll
        for (int i = 0; i < 4; ++i) {
            const int idx = tid + i * 256;
            const int kr  = idx >> 4;
            const int kc  = (idx & 15) << 2;
            float4 kv = *(const float4*)(base + DIM_ + (size_t)(k0 + kr) * rs + kc);
            Ks[kr * 65 + kc + 0] = kv.x;
            Ks[kr * 65 + kc + 1] = kv.y;
            Ks[kr * 65 + kc + 2] = kv.z;
            Ks[kr * 65 + kc + 3] = kv.w;
            float4 vv = *(const float4*)(base + 2 * DIM_ + (size_t)(k0 + kr) * rs + kc);
            *(float4*)(Vs + kr * 64 + kc) = vv;
        }
        __syncthreads();

        // scores: s[j] = Q[r] . K[c4+j]
        float s0 = 0.f, s1 = 0.f, s2 = 0.f, s3 = 0.f;
#pragma unroll
        for (int d = 0; d < 64; ++d) {
            const float q = qreg[d];
            s0 = fmaf(q, Ks[(c4 + 0) * 65 + d], s0);
            s1 = fmaf(q, Ks[(c4 + 1) * 65 + d], s1);
            s2 = fmaf(q, Ks[(c4 + 2) * 65 + d], s2);
            s3 = fmaf(q, Ks[(c4 + 3) * 65 + d], s3);
        }
        const float scale = 0.125f;  // 1/sqrt(64)
        s0 *= scale; s1 *= scale; s2 *= scale; s3 *= scale;

        float mx = fmaxf(fmaxf(s0, s1), fmaxf(s2, s3));
#pragma unroll
        for (int off = 8; off; off >>= 1)
            mx = fmaxf(mx, __shfl_xor(mx, off, 16));

        const float m_new = fmaxf(m, mx);
        const float p0 = expf(s0 - m_new);
        const float p1 = expf(s1 - m_new);
        const float p2 = expf(s2 - m_new);
        const float p3 = expf(s3 - m_new);
        float ps = p0 + p1 + p2 + p3;
#pragma unroll
        for (int off = 8; off; off >>= 1)
            ps += __shfl_xor(ps, off, 16);

        const float alpha = expf(m - m_new);   // exp(-inf)=0 on first tile
        l = l * alpha + ps;
        m = m_new;
        o.x *= alpha; o.y *= alpha; o.z *= alpha; o.w *= alpha;

        float4 pw = {p0, p1, p2, p3};
        *(float4*)(Ps + r * 64 + c4) = pw;
        __syncthreads();

        // O[r][c4..] += P[r][k] * V[k][c4..]
#pragma unroll
        for (int k = 0; k < 64; ++k) {
            const float  pv = Ps[r * 64 + k];
            const float4 vv = *(const float4*)(Vs + k * 64 + c4);
            o.x = fmaf(pv, vv.x, o.x);
            o.y = fmaf(pv, vv.y, o.y);
            o.z = fmaf(pv, vv.z, o.z);
            o.w = fmaf(pv, vv.w, o.w);
        }
    }

    const float inv = 1.0f / l;
    o.x *= inv; o.y *= inv; o.z *= inv; o.w *= inv;
    float* op = out + (size_t)(b * SEQ + q0 + r) * DIM_ + h * HDIM + c4;
    *(float4*)op = o;
}

// ---------------------------------------------------------------------------
extern "C" void kernel_launch(void* const* d_in, const int* in_sizes, int n_in,
                              void* d_out, int out_size, void* d_ws, size_t ws_size,
                              hipStream_t stream) {
    const float* x     = (const float*)d_in[0];   // (B,S,D)
    const float* w_qkv = (const float*)d_in[1];   // (3D,D)
    const float* w_out = (const float*)d_in[2];   // (D,D)
    const float* b_out = (const float*)d_in[3];   // (D,)
    float* out = (float*)d_out;                   // (B,S,D)

    float* qkv  = (float*)d_ws;                           // 4096 x 3072 fp32
    float* attn = qkv + (size_t)(BATCH * SEQ) * 3 * DIM_; // 4096 x 1024 fp32

    const int M = BATCH * SEQ;  // 4096

    // 1) qkv = x @ w_qkv^T
    gemm_abt<false><<<dim3((3 * DIM_) / 64, M / 64), 256, 0, stream>>>(
        x, w_qkv, nullptr, qkv, M, 3 * DIM_, DIM_);

    // 2) RoPE in place on q,k
    rope_kernel<<<(M * 2 * NHEADS) / 256, 256, 0, stream>>>(qkv);

    // 3) attention -> attn (B,S,D)
    attn_kernel<<<dim3(SEQ / 16, BATCH * NHEADS), 256, 0, stream>>>(qkv, attn);

    // 4) out = attn @ w_out^T + b_out
    gemm_abt<true><<<dim3(DIM_ / 64, M / 64), 256, 0, stream>>>(
        attn, w_out, b_out, out, M, DIM_, DIM_);
}

// Round 2
// 295.757 us; speedup vs baseline: 6.1906x; 6.1906x over previous
//
#include <hip/hip_runtime.h>
#include <math.h>

typedef __bf16 bf16_t;
typedef bf16_t bf16x8 __attribute__((ext_vector_type(8)));
typedef bf16_t bf16x4 __attribute__((ext_vector_type(4)));
typedef float  f32x4  __attribute__((ext_vector_type(4)));

#define DIM_   1024
#define NHEADS 16
#define HDIM   64
#define SEQ    2048
#define BATCH  2

__device__ __forceinline__ float red_max16(float v) {
    v = fmaxf(v, __shfl_xor(v, 1));
    v = fmaxf(v, __shfl_xor(v, 2));
    v = fmaxf(v, __shfl_xor(v, 4));
    v = fmaxf(v, __shfl_xor(v, 8));
    return v;
}
__device__ __forceinline__ float red_sum16(float v) {
    v += __shfl_xor(v, 1);
    v += __shfl_xor(v, 2);
    v += __shfl_xor(v, 4);
    v += __shfl_xor(v, 8);
    return v;
}

// ---------------------------------------------------------------------------
// bf16-MFMA GEMM: C[M][N] = A[M][K] * B[N][K]^T (+bias). 128x128 tile, BK=32,
// 256 threads = 4 waves in 2x2, each wave 64x64 via 4x4 subtiles of 16x16x32.
// LDS rows stride 40 bf16 (=80B, 16B-aligned; frag-read chunk starts spread
// over all 8 positions -> minimum-phase ds_read_b128).
// TA: float (convert on stage) or bf16 (plain copy). TC: bf16 or float.
// ---------------------------------------------------------------------------
template <typename TA, typename TC, bool BIAS>
__global__ __launch_bounds__(256) void gemm_mfma(const TA* __restrict__ A,
                                                 const float* __restrict__ B,
                                                 const float* __restrict__ bias,
                                                 TC* __restrict__ C,
                                                 int M, int N, int K) {
    __shared__ __align__(16) bf16_t As[128 * 40];
    __shared__ __align__(16) bf16_t Bs[128 * 40];
    const int tid  = threadIdx.x;
    const int m0   = blockIdx.y * 128;
    const int n0   = blockIdx.x * 128;
    const int w    = tid >> 6;
    const int lane = tid & 63;
    const int m16  = lane & 15;
    const int quad = lane >> 4;
    const int wm   = (w >> 1) * 64;
    const int wn   = (w & 1) * 64;

    f32x4 acc[4][4] = {};

    for (int k0 = 0; k0 < K; k0 += 32) {
        __syncthreads();
        if constexpr (sizeof(TA) == 2) {
#pragma unroll
            for (int p = 0; p < 2; ++p) {
                const int idx = tid + p * 256;
                const int row = idx >> 2, c8 = (idx & 3) * 8;
                *(bf16x8*)(&As[row * 40 + c8]) =
                    *(const bf16x8*)((const bf16_t*)A + (size_t)(m0 + row) * K + k0 + c8);
            }
        } else {
#pragma unroll
            for (int p = 0; p < 4; ++p) {
                const int idx = tid + p * 256;
                const int row = idx >> 3, c4 = (idx & 7) * 4;
                float4 v = *(const float4*)((const float*)A + (size_t)(m0 + row) * K + k0 + c4);
                bf16x4 hh = { (bf16_t)v.x, (bf16_t)v.y, (bf16_t)v.z, (bf16_t)v.w };
                *(bf16x4*)(&As[row * 40 + c4]) = hh;
            }
        }
#pragma unroll
        for (int p = 0; p < 4; ++p) {
            const int idx = tid + p * 256;
            const int row = idx >> 3, c4 = (idx & 7) * 4;
            float4 v = *(const float4*)(B + (size_t)(n0 + row) * K + k0 + c4);
            bf16x4 hh = { (bf16_t)v.x, (bf16_t)v.y, (bf16_t)v.z, (bf16_t)v.w };
            *(bf16x4*)(&Bs[row * 40 + c4]) = hh;
        }
        __syncthreads();

        bf16x8 af[4], bfr[4];
#pragma unroll
        for (int i = 0; i < 4; ++i)
            af[i] = *(const bf16x8*)(&As[(wm + i * 16 + m16) * 40 + quad * 8]);
#pragma unroll
        for (int j = 0; j < 4; ++j)
            bfr[j] = *(const bf16x8*)(&Bs[(wn + j * 16 + m16) * 40 + quad * 8]);
#pragma unroll
        for (int i = 0; i < 4; ++i)
#pragma unroll
            for (int j = 0; j < 4; ++j)
                acc[i][j] = __builtin_amdgcn_mfma_f32_16x16x32_bf16(af[i], bfr[j], acc[i][j], 0, 0, 0);
    }

#pragma unroll
    for (int i = 0; i < 4; ++i) {
#pragma unroll
        for (int j = 0; j < 4; ++j) {
            const int col = n0 + wn + j * 16 + m16;
            const float bv = BIAS ? bias[col] : 0.0f;
#pragma unroll
            for (int r = 0; r < 4; ++r) {
                const int row = m0 + wm + i * 16 + quad * 4 + r;
                C[(size_t)row * N + col] = (TC)(acc[i][j][r] + bv);
            }
        }
    }
}

// ---------------------------------------------------------------------------
// RoPE in place on bf16 qkv (q and k thirds). Block = 256 threads = 8 tokens
// x 32 (which,head). Per-block LDS sin/cos table: thread (sl=tid>>5, j=tid&31)
// computes ONE sincos for its token -> 32x fewer transcendentals.
// ---------------------------------------------------------------------------
__global__ __launch_bounds__(256) void rope_bf16(bf16_t* __restrict__ qkv) {
    __shared__ float ctab[8][32];
    __shared__ float stab[8][32];
    const int tid = threadIdx.x;
    const int sl  = tid >> 5, j = tid & 31;
    const int s   = (int)((blockIdx.x * 8 + sl) & (SEQ - 1));
    // freq_j = 10000^(-j/32) = 2^(-j*log2(10000)/32)
    const float freq = exp2f(-0.41524101186092029f * (float)j);
    float sn, cs;
    sincosf((float)s * freq, &sn, &cs);
    ctab[sl][j] = cs;
    stab[sl][j] = sn;
    __syncthreads();

    const int gid   = blockIdx.x * 256 + tid;
    const int m     = gid >> 5;        // token (b*SEQ+s); table row == sl
    const int rr    = gid & 31;
    const int which = rr >> 4;
    const int hh    = rr & 15;

    bf16_t* p = qkv + (size_t)m * (3 * DIM_) + which * DIM_ + hh * HDIM;
    union { bf16_t e[64]; bf16x8 v[8]; } X, O;
#pragma unroll
    for (int i = 0; i < 8; ++i) X.v[i] = *(const bf16x8*)(p + i * 8);
#pragma unroll
    for (int t = 0; t < 32; ++t) {
        const float x1 = (float)X.e[2 * t];
        const float x2 = (float)X.e[2 * t + 1];
        const float c  = ctab[sl][t];
        const float s2 = stab[sl][t];
        O.e[t]      = (bf16_t)(x1 * c - x2 * s2);
        O.e[32 + t] = (bf16_t)(x1 * s2 + x2 * c);
    }
#pragma unroll
    for (int i = 0; i < 8; ++i) *(bf16x8*)(p + i * 8) = O.v[i];
}

// ---------------------------------------------------------------------------
// Flash attention, bf16 MFMA. Grid (SEQ/64, B*H). 256 threads = 4 waves; wave
// w owns 16 query rows. KV streamed in 64-key tiles. K natural [key][dim],
// V transposed Vt[dim][key] (staged via per-dim scalar loads + b128 writes).
// P: C-layout -> wave-private LDS -> A-layout (verified transform).
// All LDS row strides 72 bf16 = 144B (16B-aligned, spreads b128 chunks).
// ---------------------------------------------------------------------------
__global__ __launch_bounds__(256) void attn_mfma(const bf16_t* __restrict__ qkv,
                                                 bf16_t* __restrict__ out) {
    __shared__ __align__(16) bf16_t Qs[64 * 72];
    __shared__ __align__(16) bf16_t Ks[64 * 72];
    __shared__ __align__(16) bf16_t Vt[64 * 72];
    __shared__ __align__(16) bf16_t Ps[4][16 * 72];

    const int tid  = threadIdx.x;
    const int w    = tid >> 6;
    const int lane = tid & 63;
    const int m16  = lane & 15;
    const int quad = lane >> 4;
    const int bh   = blockIdx.y;
    const int b    = bh >> 4;
    const int hh   = bh & 15;
    const int q0   = blockIdx.x * 64;

    const size_t rs = 3 * DIM_;
    const bf16_t* qbase = qkv + (size_t)(b * SEQ) * rs + hh * HDIM;
    const bf16_t* kbase = qbase + DIM_;
    const bf16_t* vbase = qbase + 2 * DIM_;

    // stage Q (64x64 bf16)
#pragma unroll
    for (int p = 0; p < 2; ++p) {
        const int idx = tid + p * 256;
        const int row = idx >> 3, c8 = (idx & 7) * 8;
        *(bf16x8*)(&Qs[row * 72 + c8]) =
            *(const bf16x8*)(qbase + (size_t)(q0 + row) * rs + c8);
    }
    __syncthreads();
    bf16x8 qf[2];
#pragma unroll
    for (int kt = 0; kt < 2; ++kt)
        qf[kt] = *(const bf16x8*)(&Qs[(w * 16 + m16) * 72 + kt * 32 + quad * 8]);

    f32x4 o[4] = {};
    float mrow[4] = {-INFINITY, -INFINITY, -INFINITY, -INFINITY};
    float lrow[4] = {};

    const int vd  = tid & 63;         // dim this thread transposes
    const int vkb = (tid >> 6) * 16;  // its 16-key block

    for (int k0 = 0; k0 < SEQ; k0 += 64) {
        __syncthreads();
        // stage K tile (natural layout)
#pragma unroll
        for (int p = 0; p < 2; ++p) {
            const int idx = tid + p * 256;
            const int row = idx >> 3, c8 = (idx & 7) * 8;
            *(bf16x8*)(&Ks[row * 72 + c8]) =
                *(const bf16x8*)(kbase + (size_t)(k0 + row) * rs + c8);
        }
        // stage V transposed: coalesced scalar loads (64 lanes = 64 contig
        // dims), contiguous b128 LDS writes along keys
        {
            union { bf16_t e[16]; bf16x8 v[2]; } tmp;
#pragma unroll
            for (int j2 = 0; j2 < 16; ++j2)
                tmp.e[j2] = vbase[(size_t)(k0 + vkb + j2) * rs + vd];
            *(bf16x8*)(&Vt[vd * 72 + vkb])     = tmp.v[0];
            *(bf16x8*)(&Vt[vd * 72 + vkb + 8]) = tmp.v[1];
        }
        __syncthreads();

        // S = Q K^T : 4 key-subtiles x 2 K-steps
        f32x4 sc[4];
#pragma unroll
        for (int n = 0; n < 4; ++n) {
            f32x4 c = {};
#pragma unroll
            for (int kt = 0; kt < 2; ++kt) {
                bf16x8 bk = *(const bf16x8*)(&Ks[(n * 16 + m16) * 72 + kt * 32 + quad * 8]);
                c = __builtin_amdgcn_mfma_f32_16x16x32_bf16(qf[kt], bk, c, 0, 0, 0);
            }
            sc[n] = c;
        }

        // online softmax in exp2 domain: csc = (1/sqrt(64)) * log2(e)
        const float csc = 0.18033688011112042f;
#pragma unroll
        for (int r = 0; r < 4; ++r) {
            const float s0 = csc * sc[0][r], s1 = csc * sc[1][r];
            const float s2 = csc * sc[2][r], s3 = csc * sc[3][r];
            float mx = fmaxf(fmaxf(s0, s1), fmaxf(s2, s3));
            mx = red_max16(mx);
            const float mnew = fmaxf(mrow[r], mx);
            const float p0 = __builtin_amdgcn_exp2f(s0 - mnew);
            const float p1 = __builtin_amdgcn_exp2f(s1 - mnew);
            const float p2 = __builtin_amdgcn_exp2f(s2 - mnew);
            const float p3 = __builtin_amdgcn_exp2f(s3 - mnew);
            const float alpha = __builtin_amdgcn_exp2f(mrow[r] - mnew);  // exp2(-inf)=0 first tile
            mrow[r] = mnew;
            const float rsum = red_sum16(p0 + p1 + p2 + p3);
            lrow[r] = lrow[r] * alpha + rsum;
            const int prow = (quad * 4 + r) * 72;
            Ps[w][prow + 0 + m16]  = (bf16_t)p0;
            Ps[w][prow + 16 + m16] = (bf16_t)p1;
            Ps[w][prow + 32 + m16] = (bf16_t)p2;
            Ps[w][prow + 48 + m16] = (bf16_t)p3;
#pragma unroll
            for (int n = 0; n < 4; ++n) o[n][r] *= alpha;
        }

        // PV: P (A-layout from LDS) x Vt (B-layout)
        bf16x8 pa[2];
#pragma unroll
        for (int kt = 0; kt < 2; ++kt)
            pa[kt] = *(const bf16x8*)(&Ps[w][m16 * 72 + kt * 32 + quad * 8]);
#pragma unroll
        for (int n = 0; n < 4; ++n) {
#pragma unroll
            for (int kt = 0; kt < 2; ++kt) {
                bf16x8 bv = *(const bf16x8*)(&Vt[(n * 16 + m16) * 72 + kt * 32 + quad * 8]);
                o[n] = __builtin_amdgcn_mfma_f32_16x16x32_bf16(pa[kt], bv, o[n], 0, 0, 0);
            }
        }
    }

    // epilogue: normalize, store bf16 (consumed by out-proj GEMM)
#pragma unroll
    for (int r = 0; r < 4; ++r) {
        const float inv = 1.0f / lrow[r];
        const size_t orow = (size_t)(b * SEQ + q0 + w * 16 + quad * 4 + r) * DIM_ + hh * HDIM;
#pragma unroll
        for (int n = 0; n < 4; ++n)
            out[orow + n * 16 + m16] = (bf16_t)(o[n][r] * inv);
    }
}

// ---------------------------------------------------------------------------
extern "C" void kernel_launch(void* const* d_in, const int* in_sizes, int n_in,
                              void* d_out, int out_size, void* d_ws, size_t ws_size,
                              hipStream_t stream) {
    const float* x     = (const float*)d_in[0];   // (B,S,D) fp32
    const float* w_qkv = (const float*)d_in[1];   // (3D,D)  fp32
    const float* w_out = (const float*)d_in[2];   // (D,D)   fp32
    const float* b_out = (const float*)d_in[3];   // (D,)    fp32
    float* out = (float*)d_out;                   // (B,S,D) fp32

    bf16_t* qkv_b  = (bf16_t*)d_ws;                              // 4096 x 3072 bf16
    bf16_t* attn_b = qkv_b + (size_t)(BATCH * SEQ) * 3 * DIM_;   // 4096 x 1024 bf16

    const int M = BATCH * SEQ;  // 4096

    // 1) qkv = x @ w_qkv^T  (bf16 out)
    gemm_mfma<float, bf16_t, false><<<dim3(3 * DIM_ / 128, M / 128), 256, 0, stream>>>(
        x, w_qkv, nullptr, qkv_b, M, 3 * DIM_, DIM_);

    // 2) RoPE in place on q,k
    rope_bf16<<<(M * 2 * NHEADS) / 256, 256, 0, stream>>>(qkv_b);

    // 3) flash attention -> attn_b (bf16)
    attn_mfma<<<dim3(SEQ / 64, BATCH * NHEADS), 256, 0, stream>>>(qkv_b, attn_b);

    // 4) out = attn @ w_out^T + b_out (fp32 out)
    gemm_mfma<bf16_t, float, true><<<dim3(DIM_ / 128, M / 128), 256, 0, stream>>>(
        attn_b, w_out, b_out, out, M, DIM_, DIM_);
}

// Round 3
// 252.890 us; speedup vs baseline: 7.2400x; 1.1695x over previous
//
#include <hip/hip_runtime.h>
#include <math.h>

typedef __bf16 bf16_t;
typedef bf16_t bf16x8 __attribute__((ext_vector_type(8)));
typedef bf16_t bf16x4 __attribute__((ext_vector_type(4)));
typedef short  s16x4  __attribute__((ext_vector_type(4)));
typedef float  f32x4  __attribute__((ext_vector_type(4)));

#define DIM_   1024
#define NHEADS 16
#define HDIM   64
#define SEQ    2048
#define BATCH  2

// log2(e)/8 : folded into q at RoPE time so PV-softmax is exp2(s) directly
#define QK_SCALE 0.18033688011112042f

__device__ __forceinline__ s16x4 as_s16x4(bf16x4 v) {
    union { bf16x4 b; s16x4 s; } u; u.b = v; return u.s;
}

// ---------------------------------------------------------------------------
// bf16-MFMA GEMM: C[M][N] = A[M][K] * B[N][K]^T (+bias). 128x128 tile, BK=32,
// 256 threads = 4 waves in 2x2, each wave 64x64 via 4x4 subtiles of 16x16x32.
// ---------------------------------------------------------------------------
template <typename TA, typename TC, bool BIAS>
__global__ __launch_bounds__(256) void gemm_mfma(const TA* __restrict__ A,
                                                 const float* __restrict__ B,
                                                 const float* __restrict__ bias,
                                                 TC* __restrict__ C,
                                                 int M, int N, int K) {
    __shared__ __align__(16) bf16_t As[128 * 40];
    __shared__ __align__(16) bf16_t Bs[128 * 40];
    const int tid  = threadIdx.x;
    const int m0   = blockIdx.y * 128;
    const int n0   = blockIdx.x * 128;
    const int w    = tid >> 6;
    const int lane = tid & 63;
    const int m16  = lane & 15;
    const int quad = lane >> 4;
    const int wm   = (w >> 1) * 64;
    const int wn   = (w & 1) * 64;

    f32x4 acc[4][4] = {};

    for (int k0 = 0; k0 < K; k0 += 32) {
        __syncthreads();
        if constexpr (sizeof(TA) == 2) {
#pragma unroll
            for (int p = 0; p < 2; ++p) {
                const int idx = tid + p * 256;
                const int row = idx >> 2, c8 = (idx & 3) * 8;
                *(bf16x8*)(&As[row * 40 + c8]) =
                    *(const bf16x8*)((const bf16_t*)A + (size_t)(m0 + row) * K + k0 + c8);
            }
        } else {
#pragma unroll
            for (int p = 0; p < 4; ++p) {
                const int idx = tid + p * 256;
                const int row = idx >> 3, c4 = (idx & 7) * 4;
                float4 v = *(const float4*)((const float*)A + (size_t)(m0 + row) * K + k0 + c4);
                bf16x4 hh = { (bf16_t)v.x, (bf16_t)v.y, (bf16_t)v.z, (bf16_t)v.w };
                *(bf16x4*)(&As[row * 40 + c4]) = hh;
            }
        }
#pragma unroll
        for (int p = 0; p < 4; ++p) {
            const int idx = tid + p * 256;
            const int row = idx >> 3, c4 = (idx & 7) * 4;
            float4 v = *(const float4*)(B + (size_t)(n0 + row) * K + k0 + c4);
            bf16x4 hh = { (bf16_t)v.x, (bf16_t)v.y, (bf16_t)v.z, (bf16_t)v.w };
            *(bf16x4*)(&Bs[row * 40 + c4]) = hh;
        }
        __syncthreads();

        bf16x8 af[4], bfr[4];
#pragma unroll
        for (int i = 0; i < 4; ++i)
            af[i] = *(const bf16x8*)(&As[(wm + i * 16 + m16) * 40 + quad * 8]);
#pragma unroll
        for (int j = 0; j < 4; ++j)
            bfr[j] = *(const bf16x8*)(&Bs[(wn + j * 16 + m16) * 40 + quad * 8]);
#pragma unroll
        for (int i = 0; i < 4; ++i)
#pragma unroll
            for (int j = 0; j < 4; ++j)
                acc[i][j] = __builtin_amdgcn_mfma_f32_16x16x32_bf16(af[i], bfr[j], acc[i][j], 0, 0, 0);
    }

#pragma unroll
    for (int i = 0; i < 4; ++i) {
#pragma unroll
        for (int j = 0; j < 4; ++j) {
            const int col = n0 + wn + j * 16 + m16;
            const float bv = BIAS ? bias[col] : 0.0f;
#pragma unroll
            for (int r = 0; r < 4; ++r) {
                const int row = m0 + wm + i * 16 + quad * 4 + r;
                C[(size_t)row * N + col] = (TC)(acc[i][j][r] + bv);
            }
        }
    }
}

// ---------------------------------------------------------------------------
// RoPE in place on bf16 qkv (q and k thirds). q additionally scaled by
// QK_SCALE (log2e/sqrt(hd)) so attention uses exp2 with no per-score mul.
// ---------------------------------------------------------------------------
__global__ __launch_bounds__(256) void rope_bf16(bf16_t* __restrict__ qkv) {
    __shared__ float ctab[8][32];
    __shared__ float stab[8][32];
    const int tid = threadIdx.x;
    const int sl  = tid >> 5, j = tid & 31;
    const int s   = (int)((blockIdx.x * 8 + sl) & (SEQ - 1));
    const float freq = exp2f(-0.41524101186092029f * (float)j);  // 10000^(-j/32)
    float sn, cs;
    sincosf((float)s * freq, &sn, &cs);
    ctab[sl][j] = cs;
    stab[sl][j] = sn;
    __syncthreads();

    const int gid   = blockIdx.x * 256 + tid;
    const int m     = gid >> 5;
    const int rr    = gid & 31;
    const int which = rr >> 4;
    const int hh    = rr & 15;
    const float osc = (which == 0) ? QK_SCALE : 1.0f;

    bf16_t* p = qkv + (size_t)m * (3 * DIM_) + which * DIM_ + hh * HDIM;
    union { bf16_t e[64]; bf16x8 v[8]; } X, O;
#pragma unroll
    for (int i = 0; i < 8; ++i) X.v[i] = *(const bf16x8*)(p + i * 8);
#pragma unroll
    for (int t = 0; t < 32; ++t) {
        const float x1 = (float)X.e[2 * t];
        const float x2 = (float)X.e[2 * t + 1];
        const float c  = ctab[sl][t];
        const float s2 = stab[sl][t];
        O.e[t]      = (bf16_t)((x1 * c - x2 * s2) * osc);
        O.e[32 + t] = (bf16_t)((x1 * s2 + x2 * c) * osc);
    }
#pragma unroll
    for (int i = 0; i < 8; ++i) *(bf16x8*)(p + i * 8) = O.v[i];
}

// ---------------------------------------------------------------------------
// Transpose V: qkv[b][s][2048 + h*64 + d] -> vt[(b*16+h)*64 + d][s]
// One block per (64 tokens, head). LDS tile 64x64.
// ---------------------------------------------------------------------------
__global__ __launch_bounds__(256) void vtrans(const bf16_t* __restrict__ qkv,
                                              bf16_t* __restrict__ vt) {
    __shared__ __align__(16) bf16_t T[64 * 72];
    const int tid = threadIdx.x;
    const int bh  = blockIdx.y;
    const int b   = bh >> 4, hh = bh & 15;
    const int s0  = blockIdx.x * 64;
    const bf16_t* src = qkv + (size_t)(b * SEQ) * 3072 + 2048 + hh * HDIM;
#pragma unroll
    for (int p = 0; p < 2; ++p) {
        const int idx = tid + p * 256;
        const int row = idx >> 3, c8 = (idx & 7) * 8;
        *(bf16x8*)(&T[row * 72 + c8]) =
            *(const bf16x8*)(src + (size_t)(s0 + row) * 3072 + c8);
    }
    __syncthreads();
#pragma unroll
    for (int p = 0; p < 2; ++p) {
        const int idx = tid + p * 256;
        const int d = idx >> 3, sc8 = (idx & 7) * 8;
        bf16x8 v;
#pragma unroll
        for (int j = 0; j < 8; ++j) v[j] = T[(sc8 + j) * 72 + d];
        *(bf16x8*)(vt + ((size_t)bh * 64 + d) * SEQ + s0 + sc8) = v;
    }
}

// ---------------------------------------------------------------------------
// Flash attention via transposed scores. Grid (SEQ/64, B*H), 256 thr = 4
// waves, wave w owns q-rows w*16..+15. Per 64-key tile:
//   S^T = K·Q^T (mfma 16x16x32): C-layout = lane(quad,m16) reg r holds
//         S^T[key=ks*16+quad*4+r][q=w*16+m16]
//   p = exp2(S^T) (q pre-scaled by log2e/8; fixed max=0 is safe: |s|<~9)
//   p registers ARE the B-fragment of mfma_f32_16x16x16bf16_1k -> PV with
//   A = V^T gives O^T[dim][q] with NO LDS round-trip for P.
//   l accumulates per-lane (all of a lane's p share q=m16); 2 shfl at end.
// ---------------------------------------------------------------------------
__global__ __launch_bounds__(256) void attn_mfma(const bf16_t* __restrict__ qkv,
                                                 const bf16_t* __restrict__ vt,
                                                 bf16_t* __restrict__ out) {
    __shared__ __align__(16) bf16_t Qs[64 * 72];
    __shared__ __align__(16) bf16_t Ks[64 * 72];
    __shared__ __align__(16) bf16_t Vt[64 * 72];

    const int tid  = threadIdx.x;
    const int w    = tid >> 6;
    const int lane = tid & 63;
    const int m16  = lane & 15;
    const int quad = lane >> 4;
    const int bh   = blockIdx.y;
    const int b    = bh >> 4;
    const int hh   = bh & 15;
    const int q0   = blockIdx.x * 64;

    const size_t rs = 3 * DIM_;
    const bf16_t* qbase = qkv + (size_t)(b * SEQ) * rs + hh * HDIM;
    const bf16_t* kbase = qbase + DIM_;
    const bf16_t* vtg   = vt + (size_t)bh * 64 * SEQ;

    // stage Q (64 q-rows x 64 dims)
#pragma unroll
    for (int p = 0; p < 2; ++p) {
        const int idx = tid + p * 256;
        const int row = idx >> 3, c8 = (idx & 7) * 8;
        *(bf16x8*)(&Qs[row * 72 + c8]) =
            *(const bf16x8*)(qbase + (size_t)(q0 + row) * rs + c8);
    }
    __syncthreads();
    bf16x8 qf[2];
#pragma unroll
    for (int kt = 0; kt < 2; ++kt)
        qf[kt] = *(const bf16x8*)(&Qs[(w * 16 + m16) * 72 + kt * 32 + quad * 8]);

    f32x4 o[4] = {};   // O^T accumulators: o[dsub][r] = O^T[dsub*16+quad*4+r][w*16+m16]
    float lp = 0.0f;   // per-lane partial row-sum (this lane's q = w*16+m16)

    for (int k0 = 0; k0 < SEQ; k0 += 64) {
        // stage K tile [key][dim] and V^T tile [dim][key]
#pragma unroll
        for (int p = 0; p < 2; ++p) {
            const int idx = tid + p * 256;
            const int row = idx >> 3, c8 = (idx & 7) * 8;
            *(bf16x8*)(&Ks[row * 72 + c8]) =
                *(const bf16x8*)(kbase + (size_t)(k0 + row) * rs + c8);
            *(bf16x8*)(&Vt[row * 72 + c8]) =
                *(const bf16x8*)(vtg + (size_t)row * SEQ + k0 + c8);
        }
        __syncthreads();

        // S^T = K . Q^T : A = K (m=key), B = Q (n=q)
        f32x4 sc[4];
#pragma unroll
        for (int ks = 0; ks < 4; ++ks) {
            f32x4 c = {};
#pragma unroll
            for (int kt = 0; kt < 2; ++kt) {
                bf16x8 ak = *(const bf16x8*)(&Ks[(ks * 16 + m16) * 72 + kt * 32 + quad * 8]);
                c = __builtin_amdgcn_mfma_f32_16x16x32_bf16(ak, qf[kt], c, 0, 0, 0);
            }
            sc[ks] = c;
        }

        // p = exp2(s); accumulate l; pack as B-fragments for K=16 PV MFMA
        s16x4 pb[4];
#pragma unroll
        for (int ks = 0; ks < 4; ++ks) {
            bf16x4 pv;
#pragma unroll
            for (int r = 0; r < 4; ++r) {
                const float p = __builtin_amdgcn_exp2f(sc[ks][r]);
                lp += p;
                pv[r] = (bf16_t)p;
            }
            pb[ks] = as_s16x4(pv);
        }

        // O^T += V^T . P : A = V^T (m=dim, k=key), B = P (n=q, k=key)
#pragma unroll
        for (int ks = 0; ks < 4; ++ks) {
#pragma unroll
            for (int ds = 0; ds < 4; ++ds) {
                bf16x4 va = *(const bf16x4*)(&Vt[(ds * 16 + m16) * 72 + ks * 16 + quad * 4]);
                o[ds] = __builtin_amdgcn_mfma_f32_16x16x16bf16_1k(as_s16x4(va), pb[ks], o[ds], 0, 0, 0);
            }
        }
        __syncthreads();
    }

    // finish l: reduce across quads (lanes with same m16)
    lp += __shfl_xor(lp, 16);
    lp += __shfl_xor(lp, 32);
    const float inv = 1.0f / lp;

    // store O (un-transpose via addressing): token row, 4 contiguous dims
    const size_t token = (size_t)(b * SEQ + q0 + w * 16 + m16);
#pragma unroll
    for (int ds = 0; ds < 4; ++ds) {
        bf16x4 ov;
#pragma unroll
        for (int r = 0; r < 4; ++r) ov[r] = (bf16_t)(o[ds][r] * inv);
        *(bf16x4*)(out + token * DIM_ + hh * HDIM + ds * 16 + quad * 4) = ov;
    }
}

// ---------------------------------------------------------------------------
extern "C" void kernel_launch(void* const* d_in, const int* in_sizes, int n_in,
                              void* d_out, int out_size, void* d_ws, size_t ws_size,
                              hipStream_t stream) {
    const float* x     = (const float*)d_in[0];
    const float* w_qkv = (const float*)d_in[1];
    const float* w_out = (const float*)d_in[2];
    const float* b_out = (const float*)d_in[3];
    float* out = (float*)d_out;

    bf16_t* qkv_b  = (bf16_t*)d_ws;                               // 4096x3072 bf16
    bf16_t* attn_b = qkv_b + (size_t)(BATCH * SEQ) * 3 * DIM_;    // 4096x1024 bf16
    bf16_t* vt_b   = attn_b + (size_t)(BATCH * SEQ) * DIM_;       // 1024x... (B*H*64 x SEQ)

    const int M = BATCH * SEQ;  // 4096

    gemm_mfma<float, bf16_t, false><<<dim3(3 * DIM_ / 128, M / 128), 256, 0, stream>>>(
        x, w_qkv, nullptr, qkv_b, M, 3 * DIM_, DIM_);

    rope_bf16<<<(M * 2 * NHEADS) / 256, 256, 0, stream>>>(qkv_b);

    vtrans<<<dim3(SEQ / 64, BATCH * NHEADS), 256, 0, stream>>>(qkv_b, vt_b);

    attn_mfma<<<dim3(SEQ / 64, BATCH * NHEADS), 256, 0, stream>>>(qkv_b, vt_b, attn_b);

    gemm_mfma<bf16_t, float, true><<<dim3(DIM_ / 128, M / 128), 256, 0, stream>>>(
        attn_b, w_out, b_out, out, M, DIM_, DIM_);
}

// Round 4
// 231.143 us; speedup vs baseline: 7.9212x; 1.0941x over previous
//
#include <hip/hip_runtime.h>
#include <math.h>

typedef __bf16 bf16_t;
typedef bf16_t bf16x8 __attribute__((ext_vector_type(8)));
typedef bf16_t bf16x4 __attribute__((ext_vector_type(4)));
typedef short  s16x4  __attribute__((ext_vector_type(4)));
typedef float  f32x4  __attribute__((ext_vector_type(4)));

#define DIM_   1024
#define NHEADS 16
#define HDIM   64
#define SEQ    2048
#define BATCH  2

// log2(e)/8 : folded into q at RoPE time so attention softmax is exp2(s)
#define QK_SCALE 0.18033688011112042f

__device__ __forceinline__ s16x4 as_s16x4(bf16x4 v) {
    union { bf16x4 b; s16x4 s; } u; u.b = v; return u.s;
}

// async global->LDS, 16 B per lane; LDS dest = wave-uniform base + lane*16
__device__ __forceinline__ void gld16(const bf16_t* g, bf16_t* l) {
    __builtin_amdgcn_global_load_lds(
        (const __attribute__((address_space(1))) void*)g,
        (__attribute__((address_space(3))) void*)l, 16, 0, 0);
}

// ---------------------------------------------------------------------------
// Fused fp32->bf16 cast of x, w_qkv, w_out (one kernel, 8 elems/thread).
// ---------------------------------------------------------------------------
#define XCNT   (4096u * 1024u)
#define WQCNT  (3072u * 1024u)
#define WOCNT  (1024u * 1024u)
__global__ __launch_bounds__(256) void cast3(const float* __restrict__ s0,
                                             const float* __restrict__ s1,
                                             const float* __restrict__ s2,
                                             bf16_t* __restrict__ d0,
                                             bf16_t* __restrict__ d1,
                                             bf16_t* __restrict__ d2) {
    size_t i = ((size_t)blockIdx.x * 256 + threadIdx.x) * 8;
    const float* s; bf16_t* d; size_t off;
    if (i < XCNT)               { s = s0; d = d0; off = i; }
    else if (i < XCNT + WQCNT)  { s = s1; d = d1; off = i - XCNT; }
    else                        { s = s2; d = d2; off = i - XCNT - WQCNT; }
    float4 a = *(const float4*)(s + off);
    float4 b = *(const float4*)(s + off + 4);
    bf16x8 o = { (bf16_t)a.x, (bf16_t)a.y, (bf16_t)a.z, (bf16_t)a.w,
                 (bf16_t)b.x, (bf16_t)b.y, (bf16_t)b.z, (bf16_t)b.w };
    *(bf16x8*)(d + off) = o;
}

// ---------------------------------------------------------------------------
// m97-style bf16 GEMM: C[M][N] = A[M][K] * B[N][K]^T. 128x128 tile, BK=32,
// 256 thr = 4 waves (2x2), global_load_lds width-16 staging into UNPADDED
// row-major LDS (layout is exactly lane-contiguous), b128 frag reads.
// QKV=true : C = qkv_b (bf16), V third written TRANSPOSED to vt instead.
// QKV=false: C = fp32 out with bias.
// ---------------------------------------------------------------------------
template <bool QKV>
__global__ __launch_bounds__(256) void gemm_lds(const bf16_t* __restrict__ A,
                                                const bf16_t* __restrict__ B,
                                                const float* __restrict__ bias,
                                                void* __restrict__ Cout,
                                                bf16_t* __restrict__ vt,
                                                int M, int N, int K) {
    __shared__ __align__(16) bf16_t As[128 * 32];
    __shared__ __align__(16) bf16_t Bs[128 * 32];
    const int tid  = threadIdx.x;
    const int m0   = blockIdx.y * 128;
    const int n0   = blockIdx.x * 128;
    const int w    = tid >> 6;
    const int lane = tid & 63;
    const int m16  = lane & 15;
    const int quad = lane >> 4;
    const int wm   = (w >> 1) * 64;
    const int wn   = (w & 1) * 64;
    const int lrow = lane >> 2;        // 0..15
    const int lcol = (lane & 3) * 8;   // 0,8,16,24

    // per-lane global srcs; per-wave uniform LDS dests
    const bf16_t* pa0 = A + (size_t)(m0 + w * 16 + lrow) * K + lcol;
    const bf16_t* pb0 = B + (size_t)(n0 + w * 16 + lrow) * K + lcol;
    bf16_t* lA0 = &As[(w * 16) * 32];
    bf16_t* lA1 = &As[(64 + w * 16) * 32];
    bf16_t* lB0 = &Bs[(w * 16) * 32];
    bf16_t* lB1 = &Bs[(64 + w * 16) * 32];

    f32x4 acc[4][4] = {};

    for (int k0 = 0; k0 < K; k0 += 32) {
        __syncthreads();
        gld16(pa0 + k0, lA0);
        gld16(pa0 + (size_t)64 * K + k0, lA1);
        gld16(pb0 + k0, lB0);
        gld16(pb0 + (size_t)64 * K + k0, lB1);
        __syncthreads();

        bf16x8 af[4], bfr[4];
#pragma unroll
        for (int i = 0; i < 4; ++i)
            af[i] = *(const bf16x8*)(&As[(wm + i * 16 + m16) * 32 + quad * 8]);
#pragma unroll
        for (int j = 0; j < 4; ++j)
            bfr[j] = *(const bf16x8*)(&Bs[(wn + j * 16 + m16) * 32 + quad * 8]);
#pragma unroll
        for (int i = 0; i < 4; ++i)
#pragma unroll
            for (int j = 0; j < 4; ++j)
                acc[i][j] = __builtin_amdgcn_mfma_f32_16x16x32_bf16(af[i], bfr[j], acc[i][j], 0, 0, 0);
    }

    if (QKV && n0 >= 2 * DIM_) {
        // V third: write transposed vt[(b*16+h)*64 + d][s]; lane's 4 regs are
        // 4 consecutive tokens -> contiguous bf16x4 along s.
        const int b      = m0 >> 11;                 // m0 / SEQ
        const int s_base = (m0 & (SEQ - 1)) + wm;
#pragma unroll
        for (int j = 0; j < 4; ++j) {
            const int cit = wn + j * 16 + m16;       // 0..127 within tile
            const int h   = ((n0 - 2 * DIM_) >> 6) + (cit >> 6);
            const int d   = cit & 63;
            bf16_t* vrow = vt + ((size_t)(b * 16 + h) * 64 + d) * SEQ + s_base;
#pragma unroll
            for (int i = 0; i < 4; ++i) {
                bf16x4 ov = { (bf16_t)acc[i][j][0], (bf16_t)acc[i][j][1],
                              (bf16_t)acc[i][j][2], (bf16_t)acc[i][j][3] };
                *(bf16x4*)(vrow + i * 16 + quad * 4) = ov;
            }
        }
    } else if (QKV) {
        bf16_t* C = (bf16_t*)Cout;
#pragma unroll
        for (int i = 0; i < 4; ++i)
#pragma unroll
            for (int j = 0; j < 4; ++j) {
                const int col = n0 + wn + j * 16 + m16;
#pragma unroll
                for (int r = 0; r < 4; ++r)
                    C[(size_t)(m0 + wm + i * 16 + quad * 4 + r) * N + col] = (bf16_t)acc[i][j][r];
            }
    } else {
        float* C = (float*)Cout;
#pragma unroll
        for (int j = 0; j < 4; ++j) {
            const int col = n0 + wn + j * 16 + m16;
            const float bv = bias[col];
#pragma unroll
            for (int i = 0; i < 4; ++i)
#pragma unroll
                for (int r = 0; r < 4; ++r)
                    C[(size_t)(m0 + wm + i * 16 + quad * 4 + r) * N + col] = acc[i][j][r] + bv;
        }
    }
}

// ---------------------------------------------------------------------------
// RoPE in place on bf16 qkv (q and k thirds). q scaled by QK_SCALE.
// ---------------------------------------------------------------------------
__global__ __launch_bounds__(256) void rope_bf16(bf16_t* __restrict__ qkv) {
    __shared__ float ctab[8][32];
    __shared__ float stab[8][32];
    const int tid = threadIdx.x;
    const int sl  = tid >> 5, j = tid & 31;
    const int s   = (int)((blockIdx.x * 8 + sl) & (SEQ - 1));
    const float freq = exp2f(-0.41524101186092029f * (float)j);  // 10000^(-j/32)
    float sn, cs;
    sincosf((float)s * freq, &sn, &cs);
    ctab[sl][j] = cs;
    stab[sl][j] = sn;
    __syncthreads();

    const int gid   = blockIdx.x * 256 + tid;
    const int m     = gid >> 5;
    const int rr    = gid & 31;
    const int which = rr >> 4;
    const int hh    = rr & 15;
    const float osc = (which == 0) ? QK_SCALE : 1.0f;

    bf16_t* p = qkv + (size_t)m * (3 * DIM_) + which * DIM_ + hh * HDIM;
    union { bf16_t e[64]; bf16x8 v[8]; } X, O;
#pragma unroll
    for (int i = 0; i < 8; ++i) X.v[i] = *(const bf16x8*)(p + i * 8);
#pragma unroll
    for (int t = 0; t < 32; ++t) {
        const float x1 = (float)X.e[2 * t];
        const float x2 = (float)X.e[2 * t + 1];
        const float c  = ctab[sl][t];
        const float s2 = stab[sl][t];
        O.e[t]      = (bf16_t)((x1 * c - x2 * s2) * osc);
        O.e[32 + t] = (bf16_t)((x1 * s2 + x2 * c) * osc);
    }
#pragma unroll
    for (int i = 0; i < 8; ++i) *(bf16x8*)(p + i * 8) = O.v[i];
}

// ---------------------------------------------------------------------------
// Flash attention via transposed scores (unchanged from R3).
// ---------------------------------------------------------------------------
__global__ __launch_bounds__(256) void attn_mfma(const bf16_t* __restrict__ qkv,
                                                 const bf16_t* __restrict__ vt,
                                                 bf16_t* __restrict__ out) {
    __shared__ __align__(16) bf16_t Qs[64 * 72];
    __shared__ __align__(16) bf16_t Ks[64 * 72];
    __shared__ __align__(16) bf16_t Vt[64 * 72];

    const int tid  = threadIdx.x;
    const int w    = tid >> 6;
    const int lane = tid & 63;
    const int m16  = lane & 15;
    const int quad = lane >> 4;
    const int bh   = blockIdx.y;
    const int b    = bh >> 4;
    const int hh   = bh & 15;
    const int q0   = blockIdx.x * 64;

    const size_t rs = 3 * DIM_;
    const bf16_t* qbase = qkv + (size_t)(b * SEQ) * rs + hh * HDIM;
    const bf16_t* kbase = qbase + DIM_;
    const bf16_t* vtg   = vt + (size_t)bh * 64 * SEQ;

#pragma unroll
    for (int p = 0; p < 2; ++p) {
        const int idx = tid + p * 256;
        const int row = idx >> 3, c8 = (idx & 7) * 8;
        *(bf16x8*)(&Qs[row * 72 + c8]) =
            *(const bf16x8*)(qbase + (size_t)(q0 + row) * rs + c8);
    }
    __syncthreads();
    bf16x8 qf[2];
#pragma unroll
    for (int kt = 0; kt < 2; ++kt)
        qf[kt] = *(const bf16x8*)(&Qs[(w * 16 + m16) * 72 + kt * 32 + quad * 8]);

    f32x4 o[4] = {};
    float lp = 0.0f;

    for (int k0 = 0; k0 < SEQ; k0 += 64) {
#pragma unroll
        for (int p = 0; p < 2; ++p) {
            const int idx = tid + p * 256;
            const int row = idx >> 3, c8 = (idx & 7) * 8;
            *(bf16x8*)(&Ks[row * 72 + c8]) =
                *(const bf16x8*)(kbase + (size_t)(k0 + row) * rs + c8);
            *(bf16x8*)(&Vt[row * 72 + c8]) =
                *(const bf16x8*)(vtg + (size_t)row * SEQ + k0 + c8);
        }
        __syncthreads();

        // S^T = K . Q^T
        f32x4 sc[4];
#pragma unroll
        for (int ks = 0; ks < 4; ++ks) {
            f32x4 c = {};
#pragma unroll
            for (int kt = 0; kt < 2; ++kt) {
                bf16x8 ak = *(const bf16x8*)(&Ks[(ks * 16 + m16) * 72 + kt * 32 + quad * 8]);
                c = __builtin_amdgcn_mfma_f32_16x16x32_bf16(ak, qf[kt], c, 0, 0, 0);
            }
            sc[ks] = c;
        }

        // p = exp2(s); per-lane l accumulation; pack as K=16 B-fragments
        s16x4 pb[4];
#pragma unroll
        for (int ks = 0; ks < 4; ++ks) {
            bf16x4 pv;
#pragma unroll
            for (int r = 0; r < 4; ++r) {
                const float p = __builtin_amdgcn_exp2f(sc[ks][r]);
                lp += p;
                pv[r] = (bf16_t)p;
            }
            pb[ks] = as_s16x4(pv);
        }

        // O^T += V^T . P
#pragma unroll
        for (int ks = 0; ks < 4; ++ks) {
#pragma unroll
            for (int ds = 0; ds < 4; ++ds) {
                bf16x4 va = *(const bf16x4*)(&Vt[(ds * 16 + m16) * 72 + ks * 16 + quad * 4]);
                o[ds] = __builtin_amdgcn_mfma_f32_16x16x16bf16_1k(as_s16x4(va), pb[ks], o[ds], 0, 0, 0);
            }
        }
        __syncthreads();
    }

    lp += __shfl_xor(lp, 16);
    lp += __shfl_xor(lp, 32);
    const float inv = 1.0f / lp;

    const size_t token = (size_t)(b * SEQ + q0 + w * 16 + m16);
#pragma unroll
    for (int ds = 0; ds < 4; ++ds) {
        bf16x4 ov;
#pragma unroll
        for (int r = 0; r < 4; ++r) ov[r] = (bf16_t)(o[ds][r] * inv);
        *(bf16x4*)(out + token * DIM_ + hh * HDIM + ds * 16 + quad * 4) = ov;
    }
}

// ---------------------------------------------------------------------------
extern "C" void kernel_launch(void* const* d_in, const int* in_sizes, int n_in,
                              void* d_out, int out_size, void* d_ws, size_t ws_size,
                              hipStream_t stream) {
    const float* x     = (const float*)d_in[0];
    const float* w_qkv = (const float*)d_in[1];
    const float* w_out = (const float*)d_in[2];
    const float* b_out = (const float*)d_in[3];
    float* out = (float*)d_out;

    const int M = BATCH * SEQ;  // 4096

    bf16_t* qkv_b  = (bf16_t*)d_ws;                            // 4096x3072
    bf16_t* attn_b = qkv_b + (size_t)M * 3 * DIM_;             // 4096x1024
    bf16_t* vt_b   = attn_b + (size_t)M * DIM_;                // 32 heads x 64 x SEQ
    bf16_t* xb     = vt_b + (size_t)BATCH * NHEADS * HDIM * SEQ;
    bf16_t* wqkvb  = xb + (size_t)M * DIM_;
    bf16_t* woutb  = wqkvb + (size_t)3 * DIM_ * DIM_;

    // 0) cast x, w_qkv, w_out to bf16
    cast3<<<(XCNT + WQCNT + WOCNT) / (256 * 8), 256, 0, stream>>>(
        x, w_qkv, w_out, xb, wqkvb, woutb);

    // 1) qkv = x @ w_qkv^T  (q,k -> qkv_b; v -> vt_b transposed)
    gemm_lds<true><<<dim3(3 * DIM_ / 128, M / 128), 256, 0, stream>>>(
        xb, wqkvb, nullptr, qkv_b, vt_b, M, 3 * DIM_, DIM_);

    // 2) RoPE in place on q,k
    rope_bf16<<<(M * 2 * NHEADS) / 256, 256, 0, stream>>>(qkv_b);

    // 3) flash attention -> attn_b
    attn_mfma<<<dim3(SEQ / 64, BATCH * NHEADS), 256, 0, stream>>>(qkv_b, vt_b, attn_b);

    // 4) out = attn @ w_out^T + b_out (fp32)
    gemm_lds<false><<<dim3(DIM_ / 128, M / 128), 256, 0, stream>>>(
        attn_b, woutb, b_out, out, nullptr, M, DIM_, DIM_);
}

// Round 5
// 230.484 us; speedup vs baseline: 7.9438x; 1.0029x over previous
//
#include <hip/hip_runtime.h>
#include <math.h>

typedef __bf16 bf16_t;
typedef bf16_t bf16x8 __attribute__((ext_vector_type(8)));
typedef bf16_t bf16x4 __attribute__((ext_vector_type(4)));
typedef short  s16x4  __attribute__((ext_vector_type(4)));
typedef float  f32x4  __attribute__((ext_vector_type(4)));

#define DIM_   1024
#define NHEADS 16
#define HDIM   64
#define SEQ    2048
#define BATCH  2

// log2(e)/8 : folded into q at RoPE time so attention softmax is exp2(s)
#define QK_SCALE 0.18033688011112042f

__device__ __forceinline__ s16x4 as_s16x4(bf16x4 v) {
    union { bf16x4 b; s16x4 s; } u; u.b = v; return u.s;
}

// async global->LDS, 16 B per lane; LDS dest = wave-uniform base + lane*16
__device__ __forceinline__ void gld16(const bf16_t* g, bf16_t* l) {
    __builtin_amdgcn_global_load_lds(
        (const __attribute__((address_space(1))) void*)g,
        (__attribute__((address_space(3))) void*)l, 16, 0, 0);
}

// ---------------------------------------------------------------------------
// Fused fp32->bf16 cast of x, w_qkv, w_out.
// ---------------------------------------------------------------------------
#define XCNT   (4096u * 1024u)
#define WQCNT  (3072u * 1024u)
#define WOCNT  (1024u * 1024u)
__global__ __launch_bounds__(256) void cast3(const float* __restrict__ s0,
                                             const float* __restrict__ s1,
                                             const float* __restrict__ s2,
                                             bf16_t* __restrict__ d0,
                                             bf16_t* __restrict__ d1,
                                             bf16_t* __restrict__ d2) {
    size_t i = ((size_t)blockIdx.x * 256 + threadIdx.x) * 8;
    const float* s; bf16_t* d; size_t off;
    if (i < XCNT)               { s = s0; d = d0; off = i; }
    else if (i < XCNT + WQCNT)  { s = s1; d = d1; off = i - XCNT; }
    else                        { s = s2; d = d2; off = i - XCNT - WQCNT; }
    float4 a = *(const float4*)(s + off);
    float4 b = *(const float4*)(s + off + 4);
    bf16x8 o = { (bf16_t)a.x, (bf16_t)a.y, (bf16_t)a.z, (bf16_t)a.w,
                 (bf16_t)b.x, (bf16_t)b.y, (bf16_t)b.z, (bf16_t)b.w };
    *(bf16x8*)(d + off) = o;
}

// ---------------------------------------------------------------------------
// m97-style bf16 GEMM (unchanged from R4): 128x128 tile, BK=32,
// global_load_lds width-16 staging, unpadded LDS, b128 frag reads.
// ---------------------------------------------------------------------------
template <bool QKV>
__global__ __launch_bounds__(256) void gemm_lds(const bf16_t* __restrict__ A,
                                                const bf16_t* __restrict__ B,
                                                const float* __restrict__ bias,
                                                void* __restrict__ Cout,
                                                bf16_t* __restrict__ vt,
                                                int M, int N, int K) {
    __shared__ __align__(16) bf16_t As[128 * 32];
    __shared__ __align__(16) bf16_t Bs[128 * 32];
    const int tid  = threadIdx.x;
    const int m0   = blockIdx.y * 128;
    const int n0   = blockIdx.x * 128;
    const int w    = tid >> 6;
    const int lane = tid & 63;
    const int m16  = lane & 15;
    const int quad = lane >> 4;
    const int wm   = (w >> 1) * 64;
    const int wn   = (w & 1) * 64;
    const int lrow = lane >> 2;
    const int lcol = (lane & 3) * 8;

    const bf16_t* pa0 = A + (size_t)(m0 + w * 16 + lrow) * K + lcol;
    const bf16_t* pb0 = B + (size_t)(n0 + w * 16 + lrow) * K + lcol;
    bf16_t* lA0 = &As[(w * 16) * 32];
    bf16_t* lA1 = &As[(64 + w * 16) * 32];
    bf16_t* lB0 = &Bs[(w * 16) * 32];
    bf16_t* lB1 = &Bs[(64 + w * 16) * 32];

    f32x4 acc[4][4] = {};

    for (int k0 = 0; k0 < K; k0 += 32) {
        __syncthreads();
        gld16(pa0 + k0, lA0);
        gld16(pa0 + (size_t)64 * K + k0, lA1);
        gld16(pb0 + k0, lB0);
        gld16(pb0 + (size_t)64 * K + k0, lB1);
        __syncthreads();

        bf16x8 af[4], bfr[4];
#pragma unroll
        for (int i = 0; i < 4; ++i)
            af[i] = *(const bf16x8*)(&As[(wm + i * 16 + m16) * 32 + quad * 8]);
#pragma unroll
        for (int j = 0; j < 4; ++j)
            bfr[j] = *(const bf16x8*)(&Bs[(wn + j * 16 + m16) * 32 + quad * 8]);
#pragma unroll
        for (int i = 0; i < 4; ++i)
#pragma unroll
            for (int j = 0; j < 4; ++j)
                acc[i][j] = __builtin_amdgcn_mfma_f32_16x16x32_bf16(af[i], bfr[j], acc[i][j], 0, 0, 0);
    }

    if (QKV && n0 >= 2 * DIM_) {
        const int b      = m0 >> 11;
        const int s_base = (m0 & (SEQ - 1)) + wm;
#pragma unroll
        for (int j = 0; j < 4; ++j) {
            const int cit = wn + j * 16 + m16;
            const int h   = ((n0 - 2 * DIM_) >> 6) + (cit >> 6);
            const int d   = cit & 63;
            bf16_t* vrow = vt + ((size_t)(b * 16 + h) * 64 + d) * SEQ + s_base;
#pragma unroll
            for (int i = 0; i < 4; ++i) {
                bf16x4 ov = { (bf16_t)acc[i][j][0], (bf16_t)acc[i][j][1],
                              (bf16_t)acc[i][j][2], (bf16_t)acc[i][j][3] };
                *(bf16x4*)(vrow + i * 16 + quad * 4) = ov;
            }
        }
    } else if (QKV) {
        bf16_t* C = (bf16_t*)Cout;
#pragma unroll
        for (int i = 0; i < 4; ++i)
#pragma unroll
            for (int j = 0; j < 4; ++j) {
                const int col = n0 + wn + j * 16 + m16;
#pragma unroll
                for (int r = 0; r < 4; ++r)
                    C[(size_t)(m0 + wm + i * 16 + quad * 4 + r) * N + col] = (bf16_t)acc[i][j][r];
            }
    } else {
        float* C = (float*)Cout;
#pragma unroll
        for (int j = 0; j < 4; ++j) {
            const int col = n0 + wn + j * 16 + m16;
            const float bv = bias[col];
#pragma unroll
            for (int i = 0; i < 4; ++i)
#pragma unroll
                for (int r = 0; r < 4; ++r)
                    C[(size_t)(m0 + wm + i * 16 + quad * 4 + r) * N + col] = acc[i][j][r] + bv;
        }
    }
}

// ---------------------------------------------------------------------------
// RoPE in place on bf16 qkv (q and k thirds). q scaled by QK_SCALE.
// ---------------------------------------------------------------------------
__global__ __launch_bounds__(256) void rope_bf16(bf16_t* __restrict__ qkv) {
    __shared__ float ctab[8][32];
    __shared__ float stab[8][32];
    const int tid = threadIdx.x;
    const int sl  = tid >> 5, j = tid & 31;
    const int s   = (int)((blockIdx.x * 8 + sl) & (SEQ - 1));
    const float freq = exp2f(-0.41524101186092029f * (float)j);  // 10000^(-j/32)
    float sn, cs;
    sincosf((float)s * freq, &sn, &cs);
    ctab[sl][j] = cs;
    stab[sl][j] = sn;
    __syncthreads();

    const int gid   = blockIdx.x * 256 + tid;
    const int m     = gid >> 5;
    const int rr    = gid & 31;
    const int which = rr >> 4;
    const int hh    = rr & 15;
    const float osc = (which == 0) ? QK_SCALE : 1.0f;

    bf16_t* p = qkv + (size_t)m * (3 * DIM_) + which * DIM_ + hh * HDIM;
    union { bf16_t e[64]; bf16x8 v[8]; } X, O;
#pragma unroll
    for (int i = 0; i < 8; ++i) X.v[i] = *(const bf16x8*)(p + i * 8);
#pragma unroll
    for (int t = 0; t < 32; ++t) {
        const float x1 = (float)X.e[2 * t];
        const float x2 = (float)X.e[2 * t + 1];
        const float c  = ctab[sl][t];
        const float s2 = stab[sl][t];
        O.e[t]      = (bf16_t)((x1 * c - x2 * s2) * osc);
        O.e[32 + t] = (bf16_t)((x1 * s2 + x2 * c) * osc);
    }
#pragma unroll
    for (int i = 0; i < 8; ++i) *(bf16x8*)(p + i * 8) = O.v[i];
}

// ---------------------------------------------------------------------------
// Flash attention, key-split waves. Grid (SEQ/64, B*H), 256 thr = 4 waves.
// Wave w owns KEY subtile w*16..+15 of every tile, for ALL 64 queries:
//   - Q held in registers (loaded once from global; no Q staging)
//   - QK: 2 b128 K-frag reads/tile (was 8); PV: 4 b64 V-frag reads (was 16)
//   - each wave accumulates partial O^T[64d][64q] over its keys; one f32
//     LDS reduction per block at the end (4 phases), plus l-sum reduce.
// ---------------------------------------------------------------------------
__global__ __launch_bounds__(256) void attn_mfma(const bf16_t* __restrict__ qkv,
                                                 const bf16_t* __restrict__ vt,
                                                 bf16_t* __restrict__ out) {
    __shared__ __align__(16) char smem[18432];
    bf16_t* Ks   = (bf16_t*)smem;            // 64 x 72
    bf16_t* Vt   = (bf16_t*)(smem + 9216);   // 64 x 72
    float*  Ored = (float*)smem;             // 4 x (16 x 65) = 16640 B
    float*  Lred = (float*)(smem + 16640);   // 4 x 64 = 1024 B

    const int tid  = threadIdx.x;
    const int w    = tid >> 6;
    const int lane = tid & 63;
    const int m16  = lane & 15;
    const int quad = lane >> 4;
    const int bh   = blockIdx.y;
    const int b    = bh >> 4;
    const int hh   = bh & 15;
    const int q0   = blockIdx.x * 64;

    const size_t rs = 3 * DIM_;
    const bf16_t* qbase = qkv + (size_t)(b * SEQ) * rs + hh * HDIM;
    const bf16_t* kbase = qbase + DIM_;
    const bf16_t* vtg   = vt + (size_t)bh * 64 * SEQ;

    // Q fragments direct to registers: qf[n][kt] = Q[q0+n*16+m16][kt*32+quad*8]
    bf16x8 qf[4][2];
#pragma unroll
    for (int n = 0; n < 4; ++n)
#pragma unroll
        for (int kt = 0; kt < 2; ++kt)
            qf[n][kt] = *(const bf16x8*)(qbase + (size_t)(q0 + n * 16 + m16) * rs + kt * 32 + quad * 8);

    f32x4 o[4][4] = {};  // o[ds][n]: partial O^T[ds*16+quad*4+r][n*16+m16] over wave's keys
    float lp[4] = {};    // per-lane partial l for q = n*16+m16 (this wave's keys, this quad)

    const int srow = tid >> 3;          // staging: 0..63 (x2)
    const int sc8  = (tid & 7) * 8;

    for (int k0 = 0; k0 < SEQ; k0 += 64) {
        // stage K tile [key][dim] and V^T tile [dim][key], stride 72
#pragma unroll
        for (int p = 0; p < 2; ++p) {
            const int row = srow + p * 32;
            *(bf16x8*)(&Ks[row * 72 + sc8]) =
                *(const bf16x8*)(kbase + (size_t)(k0 + row) * rs + sc8);
            *(bf16x8*)(&Vt[row * 72 + sc8]) =
                *(const bf16x8*)(vtg + (size_t)row * SEQ + k0 + sc8);
        }
        __syncthreads();

        // S^T (wave's 16 keys x 64 q): A = K-frag, B = Q-frag
        bf16x8 ak[2];
#pragma unroll
        for (int kt = 0; kt < 2; ++kt)
            ak[kt] = *(const bf16x8*)(&Ks[(w * 16 + m16) * 72 + kt * 32 + quad * 8]);

        bf16x4 va[4];
#pragma unroll
        for (int ds = 0; ds < 4; ++ds)
            va[ds] = *(const bf16x4*)(&Vt[(ds * 16 + m16) * 72 + w * 16 + quad * 4]);

        s16x4 pb[4];
#pragma unroll
        for (int n = 0; n < 4; ++n) {
            f32x4 c = {};
#pragma unroll
            for (int kt = 0; kt < 2; ++kt)
                c = __builtin_amdgcn_mfma_f32_16x16x32_bf16(ak[kt], qf[n][kt], c, 0, 0, 0);
            bf16x4 pv;
#pragma unroll
            for (int r = 0; r < 4; ++r) {
                const float p = __builtin_amdgcn_exp2f(c[r]);
                lp[n] += p;
                pv[r] = (bf16_t)p;
            }
            pb[n] = as_s16x4(pv);
        }

        // O^T partial += V^T . P  (K=16, keys w*16..+15)
#pragma unroll
        for (int ds = 0; ds < 4; ++ds)
#pragma unroll
            for (int n = 0; n < 4; ++n)
                o[ds][n] = __builtin_amdgcn_mfma_f32_16x16x16bf16_1k(as_s16x4(va[ds]), pb[n], o[ds][n], 0, 0, 0);
        __syncthreads();
    }

    // ---- l reduction: over quads (shfl), then over waves (LDS) ----
#pragma unroll
    for (int n = 0; n < 4; ++n) {
        lp[n] += __shfl_xor(lp[n], 16);
        lp[n] += __shfl_xor(lp[n], 32);
    }
    if (quad == 0) {
#pragma unroll
        for (int n = 0; n < 4; ++n) Lred[w * 64 + n * 16 + m16] = lp[n];
    }
    __syncthreads();
    const float linv = 1.0f / (Lred[lane] + Lred[64 + lane] + Lred[128 + lane] + Lred[192 + lane]);

    // ---- O reduction: 4 phases; wave p owns dim-quarter p ----
    const size_t obase = (size_t)(b * SEQ + q0 + lane) * DIM_ + hh * HDIM;
#pragma unroll
    for (int p = 0; p < 4; ++p) {
        __syncthreads();
#pragma unroll
        for (int n = 0; n < 4; ++n)
#pragma unroll
            for (int r = 0; r < 4; ++r)
                Ored[w * 1040 + (quad * 4 + r) * 65 + n * 16 + m16] = o[p][n][r];
        __syncthreads();
        if (w == p) {
            union { bf16_t e[16]; bf16x8 v[2]; } ob;
#pragma unroll
            for (int d = 0; d < 16; ++d) {
                const float v = Ored[d * 65 + lane] + Ored[1040 + d * 65 + lane] +
                                Ored[2080 + d * 65 + lane] + Ored[3120 + d * 65 + lane];
                ob.e[d] = (bf16_t)(v * linv);
            }
            *(bf16x8*)(out + obase + p * 16)     = ob.v[0];
            *(bf16x8*)(out + obase + p * 16 + 8) = ob.v[1];
        }
    }
}

// ---------------------------------------------------------------------------
extern "C" void kernel_launch(void* const* d_in, const int* in_sizes, int n_in,
                              void* d_out, int out_size, void* d_ws, size_t ws_size,
                              hipStream_t stream) {
    const float* x     = (const float*)d_in[0];
    const float* w_qkv = (const float*)d_in[1];
    const float* w_out = (const float*)d_in[2];
    const float* b_out = (const float*)d_in[3];
    float* out = (float*)d_out;

    const int M = BATCH * SEQ;  // 4096

    bf16_t* qkv_b  = (bf16_t*)d_ws;                            // 4096x3072
    bf16_t* attn_b = qkv_b + (size_t)M * 3 * DIM_;             // 4096x1024
    bf16_t* vt_b   = attn_b + (size_t)M * DIM_;                // 32 heads x 64 x SEQ
    bf16_t* xb     = vt_b + (size_t)BATCH * NHEADS * HDIM * SEQ;
    bf16_t* wqkvb  = xb + (size_t)M * DIM_;
    bf16_t* woutb  = wqkvb + (size_t)3 * DIM_ * DIM_;

    // 0) cast x, w_qkv, w_out to bf16
    cast3<<<(XCNT + WQCNT + WOCNT) / (256 * 8), 256, 0, stream>>>(
        x, w_qkv, w_out, xb, wqkvb, woutb);

    // 1) qkv = x @ w_qkv^T  (q,k -> qkv_b; v -> vt_b transposed)
    gemm_lds<true><<<dim3(3 * DIM_ / 128, M / 128), 256, 0, stream>>>(
        xb, wqkvb, nullptr, qkv_b, vt_b, M, 3 * DIM_, DIM_);

    // 2) RoPE in place on q,k
    rope_bf16<<<(M * 2 * NHEADS) / 256, 256, 0, stream>>>(qkv_b);

    // 3) flash attention -> attn_b
    attn_mfma<<<dim3(SEQ / 64, BATCH * NHEADS), 256, 0, stream>>>(qkv_b, vt_b, attn_b);

    // 4) out = attn @ w_out^T + b_out (fp32)
    gemm_lds<false><<<dim3(DIM_ / 128, M / 128), 256, 0, stream>>>(
        attn_b, woutb, b_out, out, nullptr, M, DIM_, DIM_);
}